// Round 22
// baseline (818.987 us; speedup 1.0000x reference)
//
#include <hip/hip_runtime.h>

#define TSEQ 512
#define NTH  128   // 2 waves: wave0 = layer0 (self-timed), wave1 = layer1; batch-16/block, 256 blocks
// R22: ZERO per-step barriers. Wave-autonomous layers at 1 wave/SIMD (512-reg budget):
//  - wave0 holds ALL of W_hh0 (128 regs) + x/bias-fused tiles (64) and runs the full
//    512-step L0 recurrence; h0 passes through 8-deep LDS slots (B-frag layout,
//    diagonal-swizzled; write 4xb64, read 2xb128).
//  - wave1 holds ALL of W_ih1+W_hh1 (256 regs) + bias (64) and runs L1; h1 is
//    wave-private (2-slot LDS ping-pong).
//  - sync: prod/cons counters, checked once per 4 steps (lead window 4-8 slots).
// Each wave owns its SIMD's trans pipe (acts = 16/lane/step = the new bottleneck).

typedef __attribute__((ext_vector_type(8))) _Float16 half8;
typedef __attribute__((ext_vector_type(4))) float f32x4;
typedef __attribute__((ext_vector_type(4))) unsigned int u32x4;

__device__ __forceinline__ unsigned pkrtz(float a, float b) {
    return __builtin_bit_cast(unsigned, __builtin_amdgcn_cvt_pkrtz(a, b));
}
// init-time RNE pack (not hot)
__device__ __forceinline__ unsigned packF16x2(float a, float b) {
    _Float16 ha = (_Float16)a, hb = (_Float16)b;
    return (unsigned)__builtin_bit_cast(unsigned short, ha) |
           ((unsigned)__builtin_bit_cast(unsigned short, hb) << 16);
}
__device__ __forceinline__ half8 packA16s(const float* w8, float s) {
    u32x4 W = { packF16x2(w8[0]*s, w8[1]*s), packF16x2(w8[2]*s, w8[3]*s),
                packF16x2(w8[4]*s, w8[5]*s), packF16x2(w8[6]*s, w8[7]*s) };
    return __builtin_bit_cast(half8, W);
}

#define MFMA(a, b, c) __builtin_amdgcn_mfma_f32_16x16x32_f16((a), (b), (c), 0, 0, 0)
#define LD128H(p) __builtin_bit_cast(half8, *(const u32x4*)(p))
#define EXP2(v) __builtin_amdgcn_exp2f(v)
#define RCP(v)  __builtin_amdgcn_rcpf(v)

// fused LSTM unit update with PRE-SCALED pre-acts (scales folded into W/b):
// ai,af,ao = -log2e * preact;  ag = 2*log2e * preact
__device__ __forceinline__ float act_fused(float ai, float af, float ag, float ao, float* c) {
    const float L2E2 = 2.88539008177792681472f;
    float ei = EXP2(ai);
    float ef = EXP2(af);
    float eg = EXP2(ag);
    float eo = EXP2(ao);
    float sf = RCP(1.0f + ef);
    float ig = (eg - 1.0f) * RCP((1.0f + ei) * (eg + 1.0f));
    float cn = fmaf(*c, sf, ig);
    *c = cn;
    float ec = EXP2(cn * L2E2);
    return (ec - 1.0f) * RCP((1.0f + eo) * (ec + 1.0f));
}

__global__ __launch_bounds__(NTH, 1)
void lstm2_pipe(const float* __restrict__ x,
                const float* __restrict__ W_ih0, const float* __restrict__ W_hh0,
                const float* __restrict__ b_ih0, const float* __restrict__ b_hh0,
                const float* __restrict__ W_ih1, const float* __restrict__ W_hh1,
                const float* __restrict__ b_ih1, const float* __restrict__ b_hh1,
                const float* __restrict__ W_fc,  const float* __restrict__ b_fc,
                float* __restrict__ out)
{
    const int tid  = threadIdx.x;
    const int lane = tid & 63;
    const int wv   = tid >> 6;        // 0: layer0 wave, 1: layer1 wave
    const int rl   = lane & 15;       // MFMA row/col index = batch col
    const int g    = lane >> 4;       // k-group / row-quad 0..3
    const int b0   = blockIdx.x * 16;

    const float NL2E  = -1.44269504088896340736f;  // i,f,o row scale
    const float PL2E2 =  2.88539008177792681472f;  // g row scale

    // h0: 8 slots (h0[t] at slot t&7), B-frag layout [16 col][32 words], diag-swizzled.
    // h1: 2 slots, wave1-private.
    __shared__ unsigned h0S[8][512];
    __shared__ unsigned h1S[2][512];
    __shared__ unsigned prodH0, consH0;

    for (int i = tid; i < 8*512; i += NTH) ((unsigned*)h0S)[i] = 0u;
    for (int i = tid; i < 2*512; i += NTH) ((unsigned*)h1S)[i] = 0u;
    if (tid == 0) { prodH0 = 0u; consH0 = 0u; }
    __syncthreads();   // init only — no barriers in the main loops

    // diagonal-swizzle offsets: reads (2 b128/k-range), writes (4 b64, one per m-group)
    const int offL = rl*32 + (((g + rl) & 7) << 2);         // units 0-31  (k-tile 0)
    const int offH = rl*32 + (((4 + g + rl) & 7) << 2);     // units 32-63 (k-tile 1)
    int woffm[4];
    #pragma unroll
    for (int m = 0; m < 4; ++m) {
        const int q = 8*m + 2*g;           // word = unit-pair (16m+4g)/2
        woffm[m] = rl*32 + ((((q >> 2) + rl) & 7) << 2) + (q & 3);
    }

    auto waitge = [&](unsigned* p, unsigned tgt) {
        while (__hip_atomic_load(p, __ATOMIC_ACQUIRE, __HIP_MEMORY_SCOPE_WORKGROUP) < tgt) {}
    };
    auto signal = [&](unsigned* p) {
        if (lane == 0)
            __hip_atomic_fetch_add(p, 1u, __ATOMIC_RELEASE, __HIP_MEMORY_SCOPE_WORKGROUP);
    };

    if (wv == 0) {
        // ================= LAYER 0 wave: whole layer, self-timed =================
        half8 Ah[2][4][4];   // [k-tile][m][G] of W_hh0 (scaled)
        half8 Axb[4][4];     // [m][G]: k0-3 = W_ih0 row, k4 = bias (g==0 lanes)
        #pragma unroll
        for (int m = 0; m < 4; ++m) {
            #pragma unroll
            for (int G = 0; G < 4; ++G) {
                const float sc = (G == 2) ? PL2E2 : NL2E;
                const int row = 64*G + 16*m + rl;
                #pragma unroll
                for (int s = 0; s < 2; ++s)
                    Ah[s][m][G] = packA16s(W_hh0 + row*64 + s*32 + g*8, sc);
                u32x4 ax = {0u, 0u, 0u, 0u};
                if (g == 0) {
                    ax.x = packF16x2(W_ih0[row*4+0]*sc, W_ih0[row*4+1]*sc);
                    ax.y = packF16x2(W_ih0[row*4+2]*sc, W_ih0[row*4+3]*sc);
                    ax.z = packF16x2((b_ih0[row] + b_hh0[row])*sc, 0.f);   // bias @ k4
                }
                Axb[m][G] = __builtin_bit_cast(half8, ax);
            }
        }
        float cst[4][4];
        #pragma unroll
        for (int m = 0; m < 4; ++m) {
            #pragma unroll
            for (int j = 0; j < 4; ++j) cst[m][j] = 0.f;
        }

        f32x4 xf = {0.f, 0.f, 0.f, 0.f};
        if (g == 0) xf = *(const f32x4*)(x + ((size_t)(b0 + rl) * TSEQ) * 4);
        unsigned bx0 = pkrtz(xf.x, xf.y), bx1 = pkrtz(xf.z, xf.w);
        const f32x4 z4 = {0.f, 0.f, 0.f, 0.f};

        for (int t = 0; t < TSEQ; ++t) {
            // backpressure: every 4 steps ensure slots t..t+3 are free (8-deep)
            if ((t & 3) == 0 && t >= 8) waitge(&consH0, (unsigned)(t - 4));
            if (g == 0 && t + 1 < TSEQ)
                xf = *(const f32x4*)(x + ((size_t)(b0 + rl) * TSEQ + (t + 1)) * 4);

            const unsigned* rP = h0S[(t + 7) & 7];   // h0[t-1] (slot 7 pre-zeroed)
            half8 B0 = LD128H(rP + offL);
            half8 B1 = LD128H(rP + offH);
            u32x4 tx = {0u, 0u, 0u, 0u};
            if (g == 0) { tx.x = bx0; tx.y = bx1; tx.z = 0x00003C00u; }  // 1.0 @ k4
            half8 Bx = __builtin_bit_cast(half8, tx);
            unsigned* wP = h0S[t & 7];

            #pragma unroll
            for (int m = 0; m < 4; ++m) {
                f32x4 a0 = MFMA(Axb[m][0], Bx, z4);
                f32x4 a1 = MFMA(Axb[m][1], Bx, z4);
                f32x4 a2 = MFMA(Axb[m][2], Bx, z4);
                f32x4 a3 = MFMA(Axb[m][3], Bx, z4);
                a0 = MFMA(Ah[0][m][0], B0, a0);  a1 = MFMA(Ah[0][m][1], B0, a1);
                a2 = MFMA(Ah[0][m][2], B0, a2);  a3 = MFMA(Ah[0][m][3], B0, a3);
                a0 = MFMA(Ah[1][m][0], B1, a0);  a1 = MFMA(Ah[1][m][1], B1, a1);
                a2 = MFMA(Ah[1][m][2], B1, a2);  a3 = MFMA(Ah[1][m][3], B1, a3);
                float hv[4];
                #pragma unroll
                for (int j = 0; j < 4; ++j)
                    hv[j] = act_fused(a0[j], a1[j], a2[j], a3[j], &cst[m][j]);
                *(uint2*)(wP + woffm[m]) = make_uint2(pkrtz(hv[0], hv[1]),
                                                      pkrtz(hv[2], hv[3]));
            }
            signal(&prodH0);                 // release: h0[t] visible
            bx0 = pkrtz(xf.x, xf.y);
            bx1 = pkrtz(xf.z, xf.w);
        }
    } else {
        // ================= LAYER 1 wave: whole layer, trails L0 by the slot lead ====
        half8 A1[4][4][4];   // [s][m][G]; s=0,1: W_ih1 (vs h0); s=2,3: W_hh1 (vs h1)
        f32x4 bias4[4][4];   // [m][G]
        #pragma unroll
        for (int m = 0; m < 4; ++m) {
            #pragma unroll
            for (int G = 0; G < 4; ++G) {
                const float sc = (G == 2) ? PL2E2 : NL2E;
                const int row = 64*G + 16*m + rl;
                #pragma unroll
                for (int s = 0; s < 4; ++s) {
                    const float* src = (s < 2) ? (W_ih1 + row*64 + s*32 + g*8)
                                               : (W_hh1 + row*64 + (s-2)*32 + g*8);
                    A1[s][m][G] = packA16s(src, sc);
                }
                const int rb = 64*G + 16*m + 4*g;
                bias4[m][G].x = (b_ih1[rb+0] + b_hh1[rb+0]) * sc;
                bias4[m][G].y = (b_ih1[rb+1] + b_hh1[rb+1]) * sc;
                bias4[m][G].z = (b_ih1[rb+2] + b_hh1[rb+2]) * sc;
                bias4[m][G].w = (b_ih1[rb+3] + b_hh1[rb+3]) * sc;
            }
        }
        float cst[4][4];
        #pragma unroll
        for (int m = 0; m < 4; ++m) {
            #pragma unroll
            for (int j = 0; j < 4; ++j) cst[m][j] = 0.f;
        }

        for (int t = 0; t < TSEQ; ++t) {
            // every 4 steps ensure h0[t..t+3] are produced
            if ((t & 3) == 0) waitge(&prodH0, (unsigned)(t + 4));

            const unsigned* r1 = h1S[(t + 1) & 1];   // h1[t-1] (slot 1 pre-zeroed)
            half8 C0 = LD128H(r1 + offL);
            half8 C1 = LD128H(r1 + offH);
            const unsigned* r0 = h0S[t & 7];         // h0[t]
            half8 B0 = LD128H(r0 + offL);
            half8 B1 = LD128H(r0 + offH);
            unsigned* wP = h1S[t & 1];

            #pragma unroll
            for (int m = 0; m < 4; ++m) {
                f32x4 a0 = MFMA(A1[2][m][0], C0, bias4[m][0]);
                f32x4 a1 = MFMA(A1[2][m][1], C0, bias4[m][1]);
                f32x4 a2 = MFMA(A1[2][m][2], C0, bias4[m][2]);
                f32x4 a3 = MFMA(A1[2][m][3], C0, bias4[m][3]);
                a0 = MFMA(A1[3][m][0], C1, a0);  a1 = MFMA(A1[3][m][1], C1, a1);
                a2 = MFMA(A1[3][m][2], C1, a2);  a3 = MFMA(A1[3][m][3], C1, a3);
                a0 = MFMA(A1[0][m][0], B0, a0);  a1 = MFMA(A1[0][m][1], B0, a1);
                a2 = MFMA(A1[0][m][2], B0, a2);  a3 = MFMA(A1[0][m][3], B0, a3);
                a0 = MFMA(A1[1][m][0], B1, a0);  a1 = MFMA(A1[1][m][1], B1, a1);
                a2 = MFMA(A1[1][m][2], B1, a2);  a3 = MFMA(A1[1][m][3], B1, a3);
                float hv[4];
                #pragma unroll
                for (int j = 0; j < 4; ++j)
                    hv[j] = act_fused(a0[j], a1[j], a2[j], a3[j], &cst[m][j]);
                *(uint2*)(wP + woffm[m]) = make_uint2(pkrtz(hv[0], hv[1]),
                                                      pkrtz(hv[2], hv[3]));
            }
            signal(&consH0);   // release: h0[t] consumed (reads retired by release)
        }

        // ---- FC epilogue: h1[511] lives in h1S[1] (511&1), frag layout ----
        if (lane < 16) {
            float accF = b_fc[0];
            const unsigned* hp = h1S[1];
            #pragma unroll
            for (int gr = 0; gr < 8; ++gr) {
                half8 h = LD128H(hp + lane*32 + (((gr + lane) & 7) << 2));
                #pragma unroll
                for (int e = 0; e < 8; ++e)
                    accF += (float)h[e] * W_fc[8*gr + e];
            }
            out[b0 + lane] = accF;
        }
    }
}

extern "C" void kernel_launch(void* const* d_in, const int* in_sizes, int n_in,
                              void* d_out, int out_size, void* d_ws, size_t ws_size,
                              hipStream_t stream) {
    const float* x     = (const float*)d_in[0];
    const float* W_ih0 = (const float*)d_in[1];
    const float* W_hh0 = (const float*)d_in[2];
    const float* b_ih0 = (const float*)d_in[3];
    const float* b_hh0 = (const float*)d_in[4];
    const float* W_ih1 = (const float*)d_in[5];
    const float* W_hh1 = (const float*)d_in[6];
    const float* b_ih1 = (const float*)d_in[7];
    const float* b_hh1 = (const float*)d_in[8];
    const float* W_fc  = (const float*)d_in[9];
    const float* b_fc  = (const float*)d_in[10];
    float* out = (float*)d_out;

    dim3 grid(4096 / 16), block(NTH);
    hipLaunchKernelGGL(lstm2_pipe, grid, block, 0, stream,
                       x, W_ih0, W_hh0, b_ih0, b_hh0,
                       W_ih1, W_hh1, b_ih1, b_hh1, W_fc, b_fc, out);
}